// Round 12
// baseline (128.753 us; speedup 1.0000x reference)
//
#include <hip/hip_runtime.h>

// Problem constants
#define NTOK   2048
#define DIM    64
#define NCODES 50000
#define THRESH 100.0f
#define BIG    3.0e38f
#define MARGIN 4.0f      // rigorous 2E bound ~2.5; 1.6x safety
#define NBLK   391       // 128-code MFMA blocks
#define BM32   1564      // 32-code screening blocks (391*4)
#define BM32P  1568      // padded row stride (pad entries = BIG)
#define NCG    64        // code groups: first 7 have 7 blocks, rest 6 (7*7+57*6=391)

typedef __attribute__((ext_vector_type(8)))  __bf16 bf16x8;
typedef __attribute__((ext_vector_type(16))) float  float16;

__device__ __forceinline__ unsigned short f2bf(float f) {
    union { float f; unsigned int u; } v; v.f = f;
    unsigned int r = v.u + 0x7FFF + ((v.u >> 16) & 1);
    return (unsigned short)(r >> 16);
}
__device__ __forceinline__ unsigned int pack2(float a, float b) {
    return (unsigned int)f2bf(a) | ((unsigned int)f2bf(b) << 16);
}

// ---------------------------------------------------------------------------
// Kernel 1 (prep): fp32 -> bf16 of codes and x, norms, bm32 pad init.
// (verbatim R9-best config)
// ---------------------------------------------------------------------------
__global__ __launch_bounds__(256)
void nn_prep_kernel(const float* __restrict__ x, const float* __restrict__ codes,
                    unsigned short* __restrict__ cbf, unsigned short* __restrict__ xbf,
                    float* __restrict__ c2, float* __restrict__ x2,
                    float* __restrict__ bm32) {
    int g = blockIdx.x * 256 + threadIdx.x;
    if (g < NTOK * 4) {  // pad slots 1564..1567 of each token row
        int t = g >> 2;
        bm32[(size_t)t * BM32P + BM32 + (g & 3)] = BIG;
    }
    int row = g >> 2;
    int seg = g & 3;
    const float* src;
    unsigned short* dst;
    float* nrm;
    if (row < NCODES) {
        src = codes + (size_t)row * DIM + seg * 16;
        dst = cbf + (size_t)row * DIM + seg * 16;
        nrm = (seg == 0) ? (c2 + row) : nullptr;
    } else if (row < NCODES + NTOK) {
        int r = row - NCODES;
        src = x + (size_t)r * DIM + seg * 16;
        dst = xbf + (size_t)r * DIM + seg * 16;
        nrm = (seg == 0) ? (x2 + r) : nullptr;
    } else {
        return;
    }
    float4 v0 = ((const float4*)src)[0];
    float4 v1 = ((const float4*)src)[1];
    float4 v2 = ((const float4*)src)[2];
    float4 v3 = ((const float4*)src)[3];
    float s = 0.f;
    s = fmaf(v0.x, v0.x, s); s = fmaf(v0.y, v0.y, s);
    s = fmaf(v0.z, v0.z, s); s = fmaf(v0.w, v0.w, s);
    s = fmaf(v1.x, v1.x, s); s = fmaf(v1.y, v1.y, s);
    s = fmaf(v1.z, v1.z, s); s = fmaf(v1.w, v1.w, s);
    s = fmaf(v2.x, v2.x, s); s = fmaf(v2.y, v2.y, s);
    s = fmaf(v2.z, v2.z, s); s = fmaf(v2.w, v2.w, s);
    s = fmaf(v3.x, v3.x, s); s = fmaf(v3.y, v3.y, s);
    s = fmaf(v3.z, v3.z, s); s = fmaf(v3.w, v3.w, s);
    uint4 lo, hi;
    lo.x = pack2(v0.x, v0.y); lo.y = pack2(v0.z, v0.w);
    lo.z = pack2(v1.x, v1.y); lo.w = pack2(v1.z, v1.w);
    hi.x = pack2(v2.x, v2.y); hi.y = pack2(v2.z, v2.w);
    hi.z = pack2(v3.x, v3.y); hi.w = pack2(v3.z, v3.w);
    *(uint4*)dst = lo;
    *(uint4*)(dst + 8) = hi;
    s += __shfl_xor(s, 1);
    s += __shfl_xor(s, 2);
    if (nrm) *nrm = s;
}

// ---------------------------------------------------------------------------
// Kernel 2 (stage A): bf16 MFMA screening, n-loop over code blocks.
// (verbatim R9-best config: 4mi x 2nj, LDS-staged, dwordx4 epilogue)
// Launched TWICE this round as a timing probe — idempotent (same bm32).
// ---------------------------------------------------------------------------
__global__ __launch_bounds__(256, 2)
void nn_stageA_kernel(const unsigned short* __restrict__ xbf,
                      const unsigned short* __restrict__ cbf,
                      const float* __restrict__ c2g,
                      float* __restrict__ bm32) {
    __shared__ __bf16 cs[128 * 72];   // code tile, 144 B row stride
    __shared__ float  c2s[128];

    const int tid  = threadIdx.x;
    const int w    = tid >> 6;
    const int lane = tid & 63;
    const int l31  = lane & 31;
    const int h    = lane >> 5;
    const int gi   = blockIdx.x;
    const int g0   = 6 * gi + min(gi, 7);
    const int nb   = (gi < 7) ? 7 : 6;
    const int t0   = blockIdx.y * 256;

    // B fragments (tokens w*64..w*64+63), loop-invariant
    bf16x8 bfr[4][2];
#pragma unroll
    for (int s = 0; s < 4; ++s)
#pragma unroll
        for (int nj = 0; nj < 2; ++nj)
            bfr[s][nj] = *(const bf16x8*)&xbf[
                (size_t)(t0 + w * 64 + nj * 32 + l31) * DIM + s * 16 + h * 8];

    // code-tile register prefetch: 128 rows x 128 B bf16; 8 lanes/row
    uint4 pr[4];
    float prc;
    auto prefetch = [&](int blk) {
        int n0 = blk * 128;
#pragma unroll
        for (int it = 0; it < 4; ++it) {
            int g = it * 256 + tid;
            int row = g >> 3, seg = g & 7;
            int n = n0 + row;
            pr[it] = (n < NCODES) ? *(const uint4*)(cbf + (size_t)n * DIM + seg * 8)
                                  : make_uint4(0, 0, 0, 0);
        }
        if (tid < 128) {
            int n = n0 + tid;
            prc = (n < NCODES) ? c2g[n] : BIG;
        }
    };
    prefetch(g0);

    for (int t = 0; t < nb; ++t) {
        const int blk = g0 + t;
        __syncthreads();   // previous iter's readers done with cs/c2s

        // regs -> LDS (conflict-free)
#pragma unroll
        for (int it = 0; it < 4; ++it) {
            int g = it * 256 + tid;
            int row = g >> 3, seg = g & 7;
            *(uint4*)&cs[row * 72 + seg * 8] = pr[it];
        }
        if (tid < 128) c2s[tid] = prc;
        if (t + 1 < nb) prefetch(blk + 1);   // latency hides under compute
        __syncthreads();

        // acc[mi][nj][r] = -c2[code_row]/2
        // C/D: col = lane&31 (token), row = (r&3) + 8*(r>>2) + 4*h (code)
        float16 acc[4][2];
#pragma unroll
        for (int mi = 0; mi < 4; ++mi) {
#pragma unroll
            for (int g2 = 0; g2 < 4; ++g2) {
                float4 c4 = *(float4*)&c2s[mi * 32 + g2 * 8 + 4 * h];
#pragma unroll
                for (int i = 0; i < 4; ++i) {
                    float iv = -0.5f * ((float*)&c4)[i];
                    acc[mi][0][g2 * 4 + i] = iv;
                    acc[mi][1][g2 * 4 + i] = iv;
                }
            }
        }

        // K = 64 in 4 steps of 16; A from LDS, B from registers
#pragma unroll
        for (int s = 0; s < 4; ++s) {
            bf16x8 a[4];
#pragma unroll
            for (int mi = 0; mi < 4; ++mi)
                a[mi] = *(bf16x8*)&cs[(mi * 32 + l31) * 72 + s * 16 + h * 8];
#pragma unroll
            for (int mi = 0; mi < 4; ++mi)
#pragma unroll
                for (int nj = 0; nj < 2; ++nj)
                    acc[mi][nj] = __builtin_amdgcn_mfma_f32_32x32x16_bf16(
                        a[mi], bfr[s][nj], acc[mi][nj], 0, 0, 0);
        }

        // epilogue: per-token max(D) per 32-code group mi; the 4 mi-values
        // for a token are in ONE lane -> single dwordx4 store per nj.
#pragma unroll
        for (int nj = 0; nj < 2; ++nj) {
            float4 o;
#pragma unroll
            for (int mi = 0; mi < 4; ++mi) {
                float m = acc[mi][nj][0];
#pragma unroll
                for (int r = 1; r < 16; ++r) m = fmaxf(m, acc[mi][nj][r]);
                m = fmaxf(m, __shfl_xor(m, 32));  // merge h halves (rows +4)
                ((float*)&o)[mi] = -2.0f * m;
            }
            if (lane < 32) {
                int token = t0 + w * 64 + nj * 32 + lane;
                *(float4*)&bm32[(size_t)token * BM32P + blk * 4] = o;
            }
        }
    }
}

// ---------------------------------------------------------------------------
// Kernel 3 (finalize): one WG per token. (verbatim R9-best config)
// ---------------------------------------------------------------------------
__global__ __launch_bounds__(256)
void nn_finalize_kernel(const float* __restrict__ x,
                        const float* __restrict__ codes,
                        const float* __restrict__ c2,
                        const float* __restrict__ x2,
                        const float* __restrict__ bm32,
                        int* __restrict__ out) {
    __shared__ float redf[8];      // [0..3] wave gmin, [4..7] wave best-v
    __shared__ int   redi[4];
    __shared__ int   queue[BM32P];
    __shared__ int   qcount;
    __shared__ float gshare;

    const int tid  = threadIdx.x;
    const int w    = tid >> 6;
    const int lane = tid & 63;
    const int t    = blockIdx.x;
    const float* bm = bm32 + (size_t)t * BM32P;

    if (tid == 0) qcount = 0;

    float v[7];
    float g = BIG;
#pragma unroll
    for (int k = 0; k < 7; ++k) {
        int b = tid + k * 256;
        v[k] = (b < BM32P) ? bm[b] : BIG;
        g = fminf(g, v[k]);
    }
#pragma unroll
    for (int m = 1; m < 64; m <<= 1) g = fminf(g, __shfl_xor(g, m));
    if (lane == 0) redf[w] = g;
    __syncthreads();
    if (tid == 0)
        gshare = fminf(fminf(redf[0], redf[1]), fminf(redf[2], redf[3])) + MARGIN;
    __syncthreads();
    const float th = gshare;

    // enqueue candidates (LDS atomic; order irrelevant — (v,id) total order)
#pragma unroll
    for (int k = 0; k < 7; ++k) {
        int b = tid + k * 256;
        if (b < BM32P && v[k] <= th) {
            int slot = atomicAdd(&qcount, 1);
            queue[slot] = b;
        }
    }
    __syncthreads();
    const int nq = qcount;

    // per-lane x half-row (half = lane&1 -> dims [0,32) or [32,64))
    const int half = lane & 1;
    float4 xh[8];
#pragma unroll
    for (int q = 0; q < 8; ++q)
        xh[q] = *(const float4*)(x + (size_t)t * DIM + half * 32 + q * 4);
    const float x2v = x2[t];

    float bv = BIG;
    int   bi = 0x7fffffff;
    for (int e = w; e < nq; e += 4) {
        int blk = queue[e];
        int n = blk * 32 + (lane >> 1);
        if (n < NCODES) {   // pair-uniform predicate
            const float4* cp = (const float4*)(codes + (size_t)n * DIM + half * 32);
            float d = 0.f;
#pragma unroll
            for (int q = 0; q < 8; ++q) {
                float4 c4 = cp[q];
                d = fmaf(xh[q].x, c4.x, d);
                d = fmaf(xh[q].y, c4.y, d);
                d = fmaf(xh[q].z, c4.z, d);
                d = fmaf(xh[q].w, c4.w, d);
            }
            d += __shfl_xor(d, 1);   // full 64-dim dot in both pair lanes
            float d2 = fmaxf(fmaf(-2.f, d, x2v + c2[n]), 0.f);
            if (d2 < bv || (d2 == bv && n < bi)) { bv = d2; bi = n; }
        }
    }
#pragma unroll
    for (int m = 1; m < 64; m <<= 1) {
        float vv = __shfl_xor(bv, m);
        int   ii = __shfl_xor(bi, m);
        if (vv < bv || (vv == bv && ii < bi)) { bv = vv; bi = ii; }
    }
    if (lane == 0) { redf[4 + w] = bv; redi[w] = bi; }
    __syncthreads();
    if (tid == 0) {
        float fb = BIG;
        int   fi = 0x7fffffff;
#pragma unroll
        for (int i = 0; i < 4; ++i) {
            float vv = redf[4 + i];
            int   ii = redi[i];
            if (vv < fb || (vv == fb && ii < fi)) { fb = vv; fi = ii; }
        }
        out[t] = (fb <= THRESH) ? fi : -1;
    }
}

// ---------------------------------------------------------------------------
// Workspace: c2[50048]f | x2[2048]f | cbf[50000*64]u16 | xbf[2048*64]u16 |
//            bm32[2048*1568]f   (~19.7 MB)
// NOTE: stageA is launched twice this round as a deliberate timing probe
// (idempotent — identical bm32 both times); dur_us - 107.7 ~= stageA cost.
// ---------------------------------------------------------------------------
extern "C" void kernel_launch(void* const* d_in, const int* in_sizes, int n_in,
                              void* d_out, int out_size, void* d_ws, size_t ws_size,
                              hipStream_t stream) {
    const float* x     = (const float*)d_in[0];  // [2,1024,64]
    const float* codes = (const float*)d_in[1];  // [50000,64]

    float* c2 = (float*)d_ws;
    float* x2 = c2 + 50048;
    unsigned short* cbf = (unsigned short*)(x2 + NTOK);
    unsigned short* xbf = cbf + (size_t)NCODES * DIM;
    float* bm32 = (float*)(xbf + (size_t)NTOK * DIM);
    int* out = (int*)d_out;

    nn_prep_kernel<<<814, 256, 0, stream>>>(x, codes, cbf, xbf, c2, x2, bm32);
    nn_stageA_kernel<<<dim3(NCG, 8), 256, 0, stream>>>(xbf, cbf, c2, bm32);
    nn_stageA_kernel<<<dim3(NCG, 8), 256, 0, stream>>>(xbf, cbf, c2, bm32);  // probe
    nn_finalize_kernel<<<NTOK, 256, 0, stream>>>(x, codes, c2, x2, bm32, out);
}

// Round 14
// 108.582 us; speedup vs baseline: 1.1858x; 1.1858x over previous
//
#include <hip/hip_runtime.h>

// Problem constants
#define NTOK   2048
#define DIM    64
#define NCODES 50000
#define THRESH 100.0f
#define BIG    3.0e38f
#define MARGIN 4.0f      // rigorous 2E bound ~2.5; 1.6x safety (HW-verified R7-R9)
#define NBLK   391       // 128-code MFMA blocks
#define BM32   1564      // 32-code screening blocks (391*4)
#define BM32P  1568      // bm32 row stride (slots >= BM32 never written/read)
#define NCG    64        // code groups: first 7 have 7 blocks, rest 6 (7*7+57*6=391)

typedef __attribute__((ext_vector_type(8)))  __bf16 bf16x8;
typedef __attribute__((ext_vector_type(16))) float  float16;

__device__ __forceinline__ unsigned short f2bf(float f) {
    union { float f; unsigned int u; } v; v.f = f;
    unsigned int r = v.u + 0x7FFF + ((v.u >> 16) & 1);
    return (unsigned short)(r >> 16);
}
__device__ __forceinline__ unsigned int pack2(float a, float b) {
    return (unsigned int)f2bf(a) | ((unsigned int)f2bf(b) << 16);
}

// ---------------------------------------------------------------------------
// Kernel 1 (stage A): bf16 MFMA screening straight from fp32 inputs.
// Grid: (64 code groups of 6-7 blocks) x (8 token supertiles of 256) = 512
// WGs = 2/CU; blockIdx.x mod 8 -> XCD swizzle (codes L2-resident).
// B fragments packed in-register from fp32 x ONCE per WG; code tiles
// prefetched from fp32 codes with inline bf16 pack + inline screening c2
// (R7-verified), LDS-staged (R9-verified), float4 epilogue (R9-verified).
// No prep kernel, no cbf/c2/xbf workspace arrays.
// ---------------------------------------------------------------------------
__global__ __launch_bounds__(256, 2)
void nn_stageA_kernel(const float* __restrict__ x,
                      const float* __restrict__ codes,
                      float* __restrict__ bm32) {
    __shared__ __bf16 cs[128 * 72];   // code tile, 144 B row stride
    __shared__ float  c2s[128];

    const int tid  = threadIdx.x;
    const int w    = tid >> 6;
    const int lane = tid & 63;
    const int l31  = lane & 31;
    const int h    = lane >> 5;
    const int gi   = blockIdx.x;
    const int g0   = 6 * gi + min(gi, 7);
    const int nb   = (gi < 7) ? 7 : 6;
    const int t0   = blockIdx.y * 256;

    // B fragments packed from fp32 x (one-time): token row, dims s*16+h*8..+8
    bf16x8 bfr[4][2];
#pragma unroll
    for (int s = 0; s < 4; ++s)
#pragma unroll
        for (int nj = 0; nj < 2; ++nj) {
            const float4* p = (const float4*)(
                x + (size_t)(t0 + w * 64 + nj * 32 + l31) * DIM + s * 16 + h * 8);
            float4 a = p[0], b = p[1];
            uint4 pk;
            pk.x = pack2(a.x, a.y); pk.y = pack2(a.z, a.w);
            pk.z = pack2(b.x, b.y); pk.w = pack2(b.z, b.w);
            bfr[s][nj] = *(bf16x8*)&pk;
        }

    // code-tile register prefetch from fp32 (R7 verbatim): 128 rows x 64
    // floats; 4 lanes/row (16 floats each), 2 slots/thread; inline c2.
    uint4 pr[2][2];
    float prc[2];
    auto prefetch = [&](int blk) {
        int n0 = blk * 128;
#pragma unroll
        for (int it = 0; it < 2; ++it) {
            int slot = it * 256 + tid;
            int row = slot >> 2, seg = slot & 3;
            int n = n0 + row;
            float4 f0, f1, f2, f3;
            if (n < NCODES) {
                const float4* p = (const float4*)(codes + (size_t)n * DIM + seg * 16);
                f0 = p[0]; f1 = p[1]; f2 = p[2]; f3 = p[3];
            } else {
                f0 = f1 = f2 = f3 = make_float4(0.f, 0.f, 0.f, 0.f);
            }
            float s = 0.f;
            s = fmaf(f0.x, f0.x, s); s = fmaf(f0.y, f0.y, s);
            s = fmaf(f0.z, f0.z, s); s = fmaf(f0.w, f0.w, s);
            s = fmaf(f1.x, f1.x, s); s = fmaf(f1.y, f1.y, s);
            s = fmaf(f1.z, f1.z, s); s = fmaf(f1.w, f1.w, s);
            s = fmaf(f2.x, f2.x, s); s = fmaf(f2.y, f2.y, s);
            s = fmaf(f2.z, f2.z, s); s = fmaf(f2.w, f2.w, s);
            s = fmaf(f3.x, f3.x, s); s = fmaf(f3.y, f3.y, s);
            s = fmaf(f3.z, f3.z, s); s = fmaf(f3.w, f3.w, s);
            pr[it][0].x = pack2(f0.x, f0.y); pr[it][0].y = pack2(f0.z, f0.w);
            pr[it][0].z = pack2(f1.x, f1.y); pr[it][0].w = pack2(f1.z, f1.w);
            pr[it][1].x = pack2(f2.x, f2.y); pr[it][1].y = pack2(f2.z, f2.w);
            pr[it][1].z = pack2(f3.x, f3.y); pr[it][1].w = pack2(f3.z, f3.w);
            // screening-only c2 (MARGIN absorbs association ulps)
            s += __shfl_xor(s, 1);
            s += __shfl_xor(s, 2);
            prc[it] = (n < NCODES) ? s : BIG;
        }
    };
    prefetch(g0);

    for (int t = 0; t < nb; ++t) {
        const int blk = g0 + t;
        __syncthreads();   // previous iter's readers done with cs/c2s

        // regs -> LDS
#pragma unroll
        for (int it = 0; it < 2; ++it) {
            int slot = it * 256 + tid;
            int row = slot >> 2, seg = slot & 3;
            *(uint4*)&cs[row * 72 + seg * 16] = pr[it][0];
            *(uint4*)&cs[row * 72 + seg * 16 + 8] = pr[it][1];
            if (seg == 0) c2s[row] = prc[it];
        }
        if (t + 1 < nb) prefetch(blk + 1);   // latency hides under compute
        __syncthreads();

        // acc[mi][nj][r] = -c2[code_row]/2
        // C/D: col = lane&31 (token), row = (r&3) + 8*(r>>2) + 4*h (code)
        float16 acc[4][2];
#pragma unroll
        for (int mi = 0; mi < 4; ++mi) {
#pragma unroll
            for (int g2 = 0; g2 < 4; ++g2) {
                float4 c4 = *(float4*)&c2s[mi * 32 + g2 * 8 + 4 * h];
#pragma unroll
                for (int i = 0; i < 4; ++i) {
                    float iv = -0.5f * ((float*)&c4)[i];
                    acc[mi][0][g2 * 4 + i] = iv;
                    acc[mi][1][g2 * 4 + i] = iv;
                }
            }
        }

        // K = 64 in 4 steps of 16; A from LDS, B from registers
#pragma unroll
        for (int s = 0; s < 4; ++s) {
            bf16x8 a[4];
#pragma unroll
            for (int mi = 0; mi < 4; ++mi)
                a[mi] = *(bf16x8*)&cs[(mi * 32 + l31) * 72 + s * 16 + h * 8];
#pragma unroll
            for (int mi = 0; mi < 4; ++mi)
#pragma unroll
                for (int nj = 0; nj < 2; ++nj)
                    acc[mi][nj] = __builtin_amdgcn_mfma_f32_32x32x16_bf16(
                        a[mi], bfr[s][nj], acc[mi][nj], 0, 0, 0);
        }

        // epilogue: per-token max(D) per 32-code group mi; 4 mi-values live
        // in one lane -> single dwordx4 store per nj. (invalid rows carry
        // ~-1.5e38 from BIG c2 -> never win; all-invalid group -> +3e38)
#pragma unroll
        for (int nj = 0; nj < 2; ++nj) {
            float4 o;
#pragma unroll
            for (int mi = 0; mi < 4; ++mi) {
                float m = acc[mi][nj][0];
#pragma unroll
                for (int r = 1; r < 16; ++r) m = fmaxf(m, acc[mi][nj][r]);
                m = fmaxf(m, __shfl_xor(m, 32));  // merge h halves (rows +4)
                ((float*)&o)[mi] = -2.0f * m;
            }
            if (lane < 32) {
                int token = t0 + w * 64 + nj * 32 + lane;
                *(float4*)&bm32[(size_t)token * BM32P + blk * 4] = o;
            }
        }
    }
}

// ---------------------------------------------------------------------------
// Kernel 2 (finalize): one WG per token. Scan 1564 blockmins once, LDS-reduce
// gmin, LDS-enqueue candidate 32-blocks, waves round-robin exact-fp32
// rescore (2 lanes/code, 8 KB/cand). c2 inline (R8-verified association);
// x2 inline with the SAME pair-shfl association (bit-identical to the old
// prep array, and per-token-uniform anyway). No global atomics.
// ---------------------------------------------------------------------------
__global__ __launch_bounds__(256)
void nn_finalize_kernel(const float* __restrict__ x,
                        const float* __restrict__ codes,
                        const float* __restrict__ bm32,
                        int* __restrict__ out) {
    __shared__ float redf[8];      // [0..3] wave gmin, [4..7] wave best-v
    __shared__ int   redi[4];
    __shared__ int   queue[BM32P];
    __shared__ int   qcount;
    __shared__ float gshare;

    const int tid  = threadIdx.x;
    const int w    = tid >> 6;
    const int lane = tid & 63;
    const int t    = blockIdx.x;
    const float* bm = bm32 + (size_t)t * BM32P;

    if (tid == 0) qcount = 0;

    float v[7];
    float g = BIG;
#pragma unroll
    for (int k = 0; k < 7; ++k) {
        int b = tid + k * 256;
        v[k] = (b < BM32) ? bm[b] : BIG;
        g = fminf(g, v[k]);
    }
#pragma unroll
    for (int m = 1; m < 64; m <<= 1) g = fminf(g, __shfl_xor(g, m));
    if (lane == 0) redf[w] = g;
    __syncthreads();
    if (tid == 0)
        gshare = fminf(fminf(redf[0], redf[1]), fminf(redf[2], redf[3])) + MARGIN;
    __syncthreads();
    const float th = gshare;

    // enqueue candidates (LDS atomic; order irrelevant — (v,id) total order)
#pragma unroll
    for (int k = 0; k < 7; ++k) {
        int b = tid + k * 256;
        if (b < BM32 && v[k] <= th) {
            int slot = atomicAdd(&qcount, 1);
            queue[slot] = b;
        }
    }
    __syncthreads();
    const int nq = qcount;

    // per-lane x half-row (half = lane&1 -> dims [0,32) or [32,64))
    const int half = lane & 1;
    float4 xh[8];
#pragma unroll
    for (int q = 0; q < 8; ++q)
        xh[q] = *(const float4*)(x + (size_t)t * DIM + half * 32 + q * 4);

    // x2 inline, identical association to the old prep: per-16 fmaf chains,
    // (s0+s1)+(s2+s3) via pair shuffle (per-token-uniform value).
    float x2v;
    {
        float sa = 0.f, sb = 0.f;
#pragma unroll
        for (int q = 0; q < 4; ++q) {
            sa = fmaf(xh[q].x, xh[q].x, sa); sa = fmaf(xh[q].y, xh[q].y, sa);
            sa = fmaf(xh[q].z, xh[q].z, sa); sa = fmaf(xh[q].w, xh[q].w, sa);
        }
#pragma unroll
        for (int q = 4; q < 8; ++q) {
            sb = fmaf(xh[q].x, xh[q].x, sb); sb = fmaf(xh[q].y, xh[q].y, sb);
            sb = fmaf(xh[q].z, xh[q].z, sb); sb = fmaf(xh[q].w, xh[q].w, sb);
        }
        float mysum = sa + sb;
        float other = __shfl_xor(mysum, 1);
        x2v = half ? (other + mysum) : (mysum + other);
    }

    float bv = BIG;
    int   bi = 0x7fffffff;
    for (int e = w; e < nq; e += 4) {
        int blk = queue[e];
        int n = blk * 32 + (lane >> 1);
        if (n < NCODES) {   // pair-uniform predicate
            const float4* cp = (const float4*)(codes + (size_t)n * DIM + half * 32);
            float4 c4[8];
#pragma unroll
            for (int q = 0; q < 8; ++q) c4[q] = cp[q];
            float d = 0.f;
#pragma unroll
            for (int q = 0; q < 8; ++q) {
                d = fmaf(xh[q].x, c4[q].x, d);
                d = fmaf(xh[q].y, c4[q].y, d);
                d = fmaf(xh[q].z, c4[q].z, d);
                d = fmaf(xh[q].w, c4[q].w, d);
            }
            d += __shfl_xor(d, 1);   // full 64-dim dot in both pair lanes
            // c2 inline (R8-verified): per-16 chains, (s0+s1)+(s2+s3)
            float sa = 0.f, sb = 0.f;
#pragma unroll
            for (int q = 0; q < 4; ++q) {
                sa = fmaf(c4[q].x, c4[q].x, sa); sa = fmaf(c4[q].y, c4[q].y, sa);
                sa = fmaf(c4[q].z, c4[q].z, sa); sa = fmaf(c4[q].w, c4[q].w, sa);
            }
#pragma unroll
            for (int q = 4; q < 8; ++q) {
                sb = fmaf(c4[q].x, c4[q].x, sb); sb = fmaf(c4[q].y, c4[q].y, sb);
                sb = fmaf(c4[q].z, c4[q].z, sb); sb = fmaf(c4[q].w, c4[q].w, sb);
            }
            float mysum = sa + sb;
            float other = __shfl_xor(mysum, 1);
            float c2v = half ? (other + mysum) : (mysum + other);
            float d2 = fmaxf(fmaf(-2.f, d, x2v + c2v), 0.f);
            if (d2 < bv || (d2 == bv && n < bi)) { bv = d2; bi = n; }
        }
    }
#pragma unroll
    for (int m = 1; m < 64; m <<= 1) {
        float vv = __shfl_xor(bv, m);
        int   ii = __shfl_xor(bi, m);
        if (vv < bv || (vv == bv && ii < bi)) { bv = vv; bi = ii; }
    }
    if (lane == 0) { redf[4 + w] = bv; redi[w] = bi; }
    __syncthreads();
    if (tid == 0) {
        float fb = BIG;
        int   fi = 0x7fffffff;
#pragma unroll
        for (int i = 0; i < 4; ++i) {
            float vv = redf[4 + i];
            int   ii = redi[i];
            if (vv < fb || (vv == fb && ii < fi)) { fb = vv; fi = ii; }
        }
        out[t] = (fb <= THRESH) ? fi : -1;
    }
}

// ---------------------------------------------------------------------------
// Workspace: bm32[2048*1568]f only (~12.8 MB). Two dispatches total.
// ---------------------------------------------------------------------------
extern "C" void kernel_launch(void* const* d_in, const int* in_sizes, int n_in,
                              void* d_out, int out_size, void* d_ws, size_t ws_size,
                              hipStream_t stream) {
    const float* x     = (const float*)d_in[0];  // [2,1024,64]
    const float* codes = (const float*)d_in[1];  // [50000,64]

    float* bm32 = (float*)d_ws;
    int* out = (int*)d_out;

    nn_stageA_kernel<<<dim3(NCG, 8), 256, 0, stream>>>(x, codes, bm32);
    nn_finalize_kernel<<<NTOK, 256, 0, stream>>>(x, codes, bm32, out);
}